// Round 1
// baseline (153.086 us; speedup 1.0000x reference)
//
#include <hip/hip_runtime.h>

// TopNGating: B=2, N=4096, DIM=2048, 8 experts, top-2, cap=640
// Outputs (concat): dispatch[2,4096,8,640], combine[2,4096,8,640], balance_loss, router_z_loss

#define DIMX 2048
#define NG   8
#define NB   2
#define NSEQ 4096
#define NTOK (NB*NSEQ)
#define CAPE 640
#define DCNT ((size_t)NTOK*NG*CAPE)   // 41943040 floats per dense output

struct Ws {
  int   e0[NTOK];
  int   e1[NTOK];
  float g0[NTOK];          // renormalized top-1 gate
  float g1[NTOK];          // renormalized top-2 gate
  int   r1[NTOK];          // should_route[1]
  int   pos0[NTOK];        // capacity slot or -1
  int   pos1[NTOK];
  float raws[(size_t)NTOK*NG];  // raw softmax gates (for density_1_proxy)
  float z2[NTOK];          // lse^2 per token
  float proxy[16];         // per (b,e) sum of raw gates over n
  int   cnt0[16];          // per (b,e) capacity-clipped top-1 count
};

// ---------------- zero-fill the two dense outputs ----------------
__global__ __launch_bounds__(256) void kzero(float4* __restrict__ p, long n4) {
  long i  = (long)blockIdx.x * blockDim.x + threadIdx.x;
  long st = (long)gridDim.x * blockDim.x;
  float4 z = make_float4(0.f, 0.f, 0.f, 0.f);
  for (; i < n4; i += st) p[i] = z;
}

// ---------------- gate logits + softmax + top2 + routing decisions ----------------
// one wave per token; W[8][2048] staged in LDS as float4 (exactly 64 KB)
__global__ __launch_bounds__(512) void kgate(const float* __restrict__ x,
                                             const float* __restrict__ W,
                                             const float* __restrict__ probs,
                                             Ws* __restrict__ ws) {
  __shared__ float4 Wl[NG * 512];
  int tid = threadIdx.x;
  for (int i = tid; i < NG * 512; i += 512) Wl[i] = ((const float4*)W)[i];
  __syncthreads();

  int wave = tid >> 6, lane = tid & 63;
  int token = blockIdx.x * 8 + wave;            // grid = NTOK/8 blocks

  const float4* xp = (const float4*)(x + (size_t)token * DIMX);
  float4 xv[8];
#pragma unroll
  for (int j = 0; j < 8; ++j) xv[j] = xp[j * 64 + lane];   // coalesced 1KB/instr

  float acc[NG] = {0.f,0.f,0.f,0.f,0.f,0.f,0.f,0.f};
#pragma unroll
  for (int j = 0; j < 8; ++j) {
    float4 xj = xv[j];
#pragma unroll
    for (int e = 0; e < NG; ++e) {
      float4 w = Wl[e * 512 + j * 64 + lane];
      acc[e] = fmaf(xj.x, w.x, acc[e]);
      acc[e] = fmaf(xj.y, w.y, acc[e]);
      acc[e] = fmaf(xj.z, w.z, acc[e]);
      acc[e] = fmaf(xj.w, w.w, acc[e]);
    }
  }
  // butterfly reduce each expert's dot across 64 lanes (all lanes end with full sums)
#pragma unroll
  for (int e = 0; e < NG; ++e) {
#pragma unroll
    for (int off = 32; off > 0; off >>= 1) acc[e] += __shfl_xor(acc[e], off, 64);
  }

  // softmax over 8 gates (redundant on all lanes, wave-uniform)
  float m = acc[0];
#pragma unroll
  for (int e = 1; e < NG; ++e) m = fmaxf(m, acc[e]);
  float ex[NG], s = 0.f;
#pragma unroll
  for (int e = 0; e < NG; ++e) { ex[e] = expf(acc[e] - m); s += ex[e]; }
  float raw[NG];
#pragma unroll
  for (int e = 0; e < NG; ++e) raw[e] = ex[e] / s;

  // top-2, ties -> lowest index (strict >)
  int e0i = 0; float g0v = raw[0];
#pragma unroll
  for (int e = 1; e < NG; ++e) if (raw[e] > g0v) { g0v = raw[e]; e0i = e; }
  int e1i = -1; float g1v = -1.f;
#pragma unroll
  for (int e = 0; e < NG; ++e) if (e != e0i && raw[e] > g1v) { g1v = raw[e]; e1i = e; }

  float denom = g0v + g1v;
  if (denom < 1e-9f) denom = 1e-9f;
  float g0n = g0v / denom, g1n = g1v / denom;

  int b = token >> 12, n = token & (NSEQ - 1);
  float p1 = probs[NB * NSEQ + b * NSEQ + n];   // probs[1][b][n]
  int r = (p1 < (g1n / 0.2f)) ? 1 : 0;          // threshold_train = 0.2 (division as in ref)

  float lse = m + logf(s);

  if (lane < NG) ws->raws[(size_t)token * NG + lane] = raw[lane];
  if (lane == 0) {
    ws->e0[token] = e0i;  ws->e1[token] = e1i;
    ws->g0[token] = g0n;  ws->g1[token] = g1n;
    ws->r1[token] = r;
    ws->z2[token] = lse * lse;
  }
}

// ---------------- per-(b,e) exclusive prefix scans with capacity ----------------
#define PADI(i) ((i) + ((i) >> 5))   // break stride-64-int bank conflict
__global__ __launch_bounds__(64) void kscan(Ws* __restrict__ ws) {
  __shared__ int m0[NSEQ + NSEQ / 32];
  __shared__ int m1[NSEQ + NSEQ / 32];   // e1 | (routed ? 0 : 8)
  int be = blockIdx.x, b = be >> 3, e = be & 7, lane = threadIdx.x;
  int base = b * NSEQ;

  for (int i = lane; i < NSEQ; i += 64) {
    m0[PADI(i)] = ws->e0[base + i];
    m1[PADI(i)] = ws->e1[base + i] | (ws->r1[base + i] ? 0 : 8);
  }
  // density_1_proxy partial: sum raw gates for this (b,e)
  float ps = 0.f;
  for (int i = lane; i < NSEQ; i += 64) ps += ws->raws[(size_t)(base + i) * NG + e];
#pragma unroll
  for (int off = 32; off > 0; off >>= 1) ps += __shfl_xor(ps, off, 64);
  __syncthreads();

  // ---- k = 0 (always routed) ----
  int cnt = 0;
  for (int i = 0; i < 64; ++i) cnt += (m0[PADI(lane * 64 + i)] == e);
  int incl = cnt;
#pragma unroll
  for (int off = 1; off < 64; off <<= 1) { int v = __shfl_up(incl, off, 64); if (lane >= off) incl += v; }
  int excl = incl - cnt;
  int tot  = __shfl(incl, 63, 64);
  int c0   = min(tot, CAPE);
  int p = excl;
  for (int i = 0; i < 64; ++i) {
    int nn = lane * 64 + i;
    if (m0[PADI(nn)] == e) { ws->pos0[base + nn] = (p < CAPE) ? p : -1; ++p; }
  }

  // ---- k = 1 (offset by capacity-clipped top-1 count) ----
  cnt = 0;
  for (int i = 0; i < 64; ++i) cnt += (m1[PADI(lane * 64 + i)] == e);
  incl = cnt;
#pragma unroll
  for (int off = 1; off < 64; off <<= 1) { int v = __shfl_up(incl, off, 64); if (lane >= off) incl += v; }
  excl = incl - cnt;
  p = excl;
  for (int i = 0; i < 64; ++i) {
    int nn = lane * 64 + i;
    int v = m1[PADI(nn)];
    if ((v & 7) == e) {
      if (v == e) { int pp = p + c0; ws->pos1[base + nn] = (pp < CAPE) ? pp : -1; ++p; }
      else        { ws->pos1[base + nn] = -1; }
    }
  }

  if (lane == 0) { ws->proxy[be] = ps; ws->cnt0[be] = c0; }
}

// ---------------- losses ----------------
__global__ __launch_bounds__(256) void kloss(const Ws* __restrict__ ws, float* __restrict__ outs) {
  __shared__ float red[256];
  int t = threadIdx.x;
  float s = 0.f;
  for (int i = t; i < NTOK; i += 256) s += ws->z2[i];
  red[t] = s; __syncthreads();
  for (int st = 128; st > 0; st >>= 1) { if (t < st) red[t] += red[t + st]; __syncthreads(); }
  if (t == 0) {
    float bal = 0.f;
    for (int i = 0; i < 16; ++i)
      bal += (ws->proxy[i] * (1.f / NSEQ)) * ((float)ws->cnt0[i] * (1.f / NSEQ));
    bal = bal * (64.f / 16.f);          // mean over 16 (b,e) then * NUM_GATES^2
    outs[0] = bal;
    outs[1] = red[0] / (float)NTOK;
  }
}

// ---------------- scatter nonzeros into dispatch/combine ----------------
__global__ __launch_bounds__(256) void kscatter(const Ws* __restrict__ ws,
                                                float* __restrict__ dispatch,
                                                float* __restrict__ combine) {
  int token = blockIdx.x * blockDim.x + threadIdx.x;
  if (token >= NTOK) return;
  size_t base = (size_t)token * (NG * CAPE);
  int p0 = ws->pos0[token];
  if (p0 >= 0) {
    size_t o = base + (size_t)ws->e0[token] * CAPE + p0;
    combine[o] = ws->g0[token];
    dispatch[o] = 1.f;
  }
  int p1 = ws->pos1[token];
  if (p1 >= 0) {
    size_t o = base + (size_t)ws->e1[token] * CAPE + p1;
    combine[o] = ws->g1[token];
    dispatch[o] = 1.f;
  }
}

extern "C" void kernel_launch(void* const* d_in, const int* in_sizes, int n_in,
                              void* d_out, int out_size, void* d_ws, size_t ws_size,
                              hipStream_t stream) {
  const float* x     = (const float*)d_in[0];
  const float* W     = (const float*)d_in[1];
  const float* probs = (const float*)d_in[2];
  float* out = (float*)d_out;
  Ws* ws = (Ws*)d_ws;

  long n4 = (long)(2 * DCNT) / 4;  // dispatch+combine in float4s
  kzero<<<4096, 256, 0, stream>>>((float4*)out, n4);
  kgate<<<NTOK / 8, 512, 0, stream>>>(x, W, probs, ws);
  kscan<<<16, 64, 0, stream>>>(ws);
  kloss<<<1, 256, 0, stream>>>(ws, out + 2 * DCNT);
  kscatter<<<NTOK / 256, 256, 0, stream>>>(ws, out, out + DCNT);
}

// Round 2
// 93.226 us; speedup vs baseline: 1.6421x; 1.6421x over previous
//
#include <hip/hip_runtime.h>

// TopNGating: B=2, N=4096, DIM=2048, 8 experts, top-2, cap=640
// Outputs (concat): dispatch[2,4096,8,640], combine[2,4096,8,640], balance_loss, router_z_loss

#define DIMX 2048
#define NG   8
#define NB   2
#define NSEQ 4096
#define NTOK (NB*NSEQ)
#define CAPE 640
#define ROW  (NG*CAPE)                 // 5120 floats per token per tensor
#define DCNT ((size_t)NTOK*ROW)        // 41943040 floats per dense output

struct Ws {
  int   pk[NTOK];                 // e0 | e1<<4 | routed1<<8
  float g0[NTOK];                 // renormalized top-1 gate
  float g1[NTOK];                 // renormalized top-2 gate
  float z2[NTOK];                 // lse^2 per token
  float raws[(size_t)NTOK*NG];    // raw softmax gates
  int   pos0[NTOK];               // capacity slot or -1
  int   pos1[NTOK];
  float proxy[16];                // per (b,e) sum of raw gates over n
  int   cnt0[16];                 // per (b,e) capacity-clipped top-1 count
};

// ---------------- gate logits + softmax + top2 + routing decisions ----------------
// one wave per token; W[8][2048] staged in LDS as float4 (exactly 64 KB)
__global__ __launch_bounds__(512) void kgate(const float* __restrict__ x,
                                             const float* __restrict__ W,
                                             const float* __restrict__ probs,
                                             Ws* __restrict__ ws) {
  __shared__ float4 Wl[NG * 512];
  int tid = threadIdx.x;
  for (int i = tid; i < NG * 512; i += 512) Wl[i] = ((const float4*)W)[i];
  __syncthreads();

  int wave = tid >> 6, lane = tid & 63;
  int token = blockIdx.x * 8 + wave;            // grid = NTOK/8 blocks

  const float4* xp = (const float4*)(x + (size_t)token * DIMX);
  float4 xv[8];
#pragma unroll
  for (int j = 0; j < 8; ++j) xv[j] = xp[j * 64 + lane];   // coalesced 1KB/instr

  float acc[NG] = {0.f,0.f,0.f,0.f,0.f,0.f,0.f,0.f};
#pragma unroll
  for (int j = 0; j < 8; ++j) {
    float4 xj = xv[j];
#pragma unroll
    for (int e = 0; e < NG; ++e) {
      float4 w = Wl[e * 512 + j * 64 + lane];
      acc[e] = fmaf(xj.x, w.x, acc[e]);
      acc[e] = fmaf(xj.y, w.y, acc[e]);
      acc[e] = fmaf(xj.z, w.z, acc[e]);
      acc[e] = fmaf(xj.w, w.w, acc[e]);
    }
  }
#pragma unroll
  for (int e = 0; e < NG; ++e) {
#pragma unroll
    for (int off = 32; off > 0; off >>= 1) acc[e] += __shfl_xor(acc[e], off, 64);
  }

  // softmax over 8 gates (wave-uniform, redundant on all lanes)
  float m = acc[0];
#pragma unroll
  for (int e = 1; e < NG; ++e) m = fmaxf(m, acc[e]);
  float ex[NG], s = 0.f;
#pragma unroll
  for (int e = 0; e < NG; ++e) { ex[e] = expf(acc[e] - m); s += ex[e]; }
  float raw[NG];
#pragma unroll
  for (int e = 0; e < NG; ++e) raw[e] = ex[e] / s;

  // top-2, ties -> lowest index (strict >)
  int e0i = 0; float g0v = raw[0];
#pragma unroll
  for (int e = 1; e < NG; ++e) if (raw[e] > g0v) { g0v = raw[e]; e0i = e; }
  int e1i = -1; float g1v = -1.f;
#pragma unroll
  for (int e = 0; e < NG; ++e) if (e != e0i && raw[e] > g1v) { g1v = raw[e]; e1i = e; }

  float denom = g0v + g1v;
  if (denom < 1e-9f) denom = 1e-9f;
  float g0n = g0v / denom, g1n = g1v / denom;

  int b = token >> 12, n = token & (NSEQ - 1);
  float p1 = probs[NB * NSEQ + b * NSEQ + n];   // probs[1][b][n]
  int r = (p1 < (g1n / 0.2f)) ? 1 : 0;          // threshold_train = 0.2

  float lse = m + logf(s);

  if (lane < NG) ws->raws[(size_t)token * NG + lane] = raw[lane];
  if (lane == 0) {
    ws->pk[token] = e0i | (e1i << 4) | (r << 8);
    ws->g0[token] = g0n;  ws->g1[token] = g1n;
    ws->z2[token] = lse * lse;
  }
}

// ---------------- per-(b,e) exclusive prefix scans with capacity (256-thread block scan) ----------------
__global__ __launch_bounds__(256) void kscan(Ws* __restrict__ ws) {
  __shared__ int   wtot[4];
  __shared__ float wsum[4];
  int be = blockIdx.x, b = be >> 3, e = be & 7;
  int t = threadIdx.x, wave = t >> 6, lane = t & 63;
  int base = b * NSEQ;

  // each thread owns 16 consecutive tokens; wave covers contiguous 4KB -> coalesced int4
  int pk[16];
  {
    const int4* pp = (const int4*)(ws->pk + base + t * 16);
#pragma unroll
    for (int j = 0; j < 4; ++j) {
      int4 v = pp[j];
      pk[4*j] = v.x; pk[4*j+1] = v.y; pk[4*j+2] = v.z; pk[4*j+3] = v.w;
    }
  }

  // density_1_proxy partial: sum raw gates for this (b,e)
  float ps = 0.f;
#pragma unroll
  for (int i = 0; i < 16; ++i) ps += ws->raws[(size_t)(base + t * 16 + i) * NG + e];
#pragma unroll
  for (int off = 32; off > 0; off >>= 1) ps += __shfl_xor(ps, off, 64);
  if (lane == 0) wsum[wave] = ps;

  // ---- k = 0 (always routed) ----
  int cnt = 0;
#pragma unroll
  for (int i = 0; i < 16; ++i) cnt += ((pk[i] & 15) == e);
  int incl = cnt;
#pragma unroll
  for (int off = 1; off < 64; off <<= 1) { int v = __shfl_up(incl, off, 64); if (lane >= off) incl += v; }
  if (lane == 63) wtot[wave] = incl;
  __syncthreads();
  int woff = 0, tot = 0;
#pragma unroll
  for (int w = 0; w < 4; ++w) { int v = wtot[w]; tot += v; if (w < wave) woff += v; }
  int c0 = min(tot, CAPE);
  int p = woff + incl - cnt;          // exclusive prefix for this thread's first token
#pragma unroll
  for (int i = 0; i < 16; ++i) {
    if ((pk[i] & 15) == e) { ws->pos0[base + t * 16 + i] = (p < CAPE) ? p : -1; ++p; }
  }
  __syncthreads();   // wtot reuse

  // ---- k = 1 (offset by capacity-clipped top-1 count) ----
  cnt = 0;
#pragma unroll
  for (int i = 0; i < 16; ++i) cnt += ((((pk[i] >> 4) & 15) == e) && (pk[i] & 0x100));
  incl = cnt;
#pragma unroll
  for (int off = 1; off < 64; off <<= 1) { int v = __shfl_up(incl, off, 64); if (lane >= off) incl += v; }
  if (lane == 63) wtot[wave] = incl;
  __syncthreads();
  woff = 0;
#pragma unroll
  for (int w = 0; w < 4; ++w) { int v = wtot[w]; if (w < wave) woff += v; }
  p = woff + incl - cnt;
#pragma unroll
  for (int i = 0; i < 16; ++i) {
    if (((pk[i] >> 4) & 15) == e) {
      if (pk[i] & 0x100) { int q = p + c0; ws->pos1[base + t * 16 + i] = (q < CAPE) ? q : -1; ++p; }
      else               { ws->pos1[base + t * 16 + i] = -1; }
    }
  }

  if (t == 0) {
    ws->proxy[be] = wsum[0] + wsum[1] + wsum[2] + wsum[3];
    ws->cnt0[be]  = c0;
  }
}

// ---------------- fused zero-fill + scatter + losses ----------------
// one 256-thread block per token: writes that token's 5120-float row of
// dispatch AND combine in a single streaming pass, nonzeros inserted inline.
__global__ __launch_bounds__(256) void kout(const Ws* __restrict__ ws, float* __restrict__ out) {
  int token = blockIdx.x;
  int t = threadIdx.x;
  int pkv = ws->pk[token];
  int e0 = pkv & 15, e1 = (pkv >> 4) & 15;
  int p0 = ws->pos0[token], p1 = ws->pos1[token];
  float g0 = ws->g0[token], g1 = ws->g1[token];
  int o0 = (p0 >= 0) ? e0 * CAPE + p0 : -16;    // -16: never matches any rel in [0,4)
  int o1 = (p1 >= 0) ? e1 * CAPE + p1 : -16;

  float* drow = out + (size_t)token * ROW;
  float* crow = out + DCNT + (size_t)token * ROW;

#pragma unroll
  for (int c = 0; c < 5; ++c) {
    int off = c * 1024 + t * 4;
    int r0 = o0 - off, r1 = o1 - off;
    float4 dv, cv;
    dv.x = ((r0 == 0) | (r1 == 0)) ? 1.f : 0.f;
    dv.y = ((r0 == 1) | (r1 == 1)) ? 1.f : 0.f;
    dv.z = ((r0 == 2) | (r1 == 2)) ? 1.f : 0.f;
    dv.w = ((r0 == 3) | (r1 == 3)) ? 1.f : 0.f;
    cv.x = (r0 == 0) ? g0 : ((r1 == 0) ? g1 : 0.f);
    cv.y = (r0 == 1) ? g0 : ((r1 == 1) ? g1 : 0.f);
    cv.z = (r0 == 2) ? g0 : ((r1 == 2) ? g1 : 0.f);
    cv.w = (r0 == 3) ? g0 : ((r1 == 3) ? g1 : 0.f);
    *(float4*)(drow + off) = dv;
    *(float4*)(crow + off) = cv;
  }

  if (token == 0) {
    __shared__ float red[256];
    float s = 0.f;
    const float4* zz = (const float4*)ws->z2;
    for (int i = t; i < NTOK / 4; i += 256) { float4 v = zz[i]; s += v.x + v.y + v.z + v.w; }
    red[t] = s; __syncthreads();
    for (int st = 128; st > 0; st >>= 1) { if (t < st) red[t] += red[t + st]; __syncthreads(); }
    if (t == 0) {
      float bal = 0.f;
      for (int i = 0; i < 16; ++i)
        bal += (ws->proxy[i] * (1.f / NSEQ)) * ((float)ws->cnt0[i] * (1.f / NSEQ));
      out[2 * DCNT]     = bal * (64.f / 16.f);     // mean over 16 (b,e) then * NUM_GATES^2
      out[2 * DCNT + 1] = red[0] / (float)NTOK;
    }
  }
}

extern "C" void kernel_launch(void* const* d_in, const int* in_sizes, int n_in,
                              void* d_out, int out_size, void* d_ws, size_t ws_size,
                              hipStream_t stream) {
  const float* x     = (const float*)d_in[0];
  const float* W     = (const float*)d_in[1];
  const float* probs = (const float*)d_in[2];
  float* out = (float*)d_out;
  Ws* ws = (Ws*)d_ws;

  kgate<<<NTOK / 8, 512, 0, stream>>>(x, W, probs, ws);
  kscan<<<16, 256, 0, stream>>>(ws);
  kout<<<NTOK, 256, 0, stream>>>(ws, out);
}